// Round 6
// baseline (248.529 us; speedup 1.0000x reference)
//
#include <hip/hip_runtime.h>
#include <stdint.h>

// DeformableFusionAcrossFocus — round 6: LDS DMA prefetch (no register prefetch -> no spills).
// x:(2,64,16,96,96) f32 | w_off:(6,64,3) | b_off:(6) | w_def:(64,64,3) | b_def:(64) -> out f32
// Tile = (b,h,8w): pos = n*8+w in [0,128). 2304 tiles = 768 persistent blocks x 3.
// Block p -> tile swz(p) + 768j; swz pairs (p,p+8) onto adjacent w-tiles for L2 line sharing.
// k-permutation kk -> (c = kk&63, k3 = kk>>6), shared by A-frag prep and B-frag builders.
// Waves split by pos: wave wv owns nt = 2wv..2wv+1 (32 pos), all 64 output channels.
//
// Per-tile flow: [top barrier: DMA drained] transpose xraw->xs_t | [barrier] issue next DMA |
// conv(MFMA)+params (wave-local, no barrier) | GEMM | [barrier] 2-pass staged epilogue.

typedef __attribute__((ext_vector_type(8))) short short8;
typedef __attribute__((ext_vector_type(4))) float f32x4;

// LDS (bytes):
//  [0,18432)      xs_t bf16 [pos][72 shorts] (row stride 144B, 64 c used, +8 pad)
//  [0,16896)      epilogue staging f32 [32 o][132] (2 passes; xs_t dead post-GEMM)
//  [18432,21504)  offs f32 [6][128] (wave-local producer/consumer)
//  [21504,54272)  xraw fp32 [row=c*16+n][8 w] — global_load_lds target (next-tile prefetch)
#define XT_OFF   0
#define OFFS_OFF 18432
#define XR_OFF   21504
#define LDS_BYTES 54272   // 3 blocks/CU (3*54272 = 162816 <= 163840)

__device__ __forceinline__ short f2bf(float f) {
  union { float f; uint32_t u; } v; v.f = f;
  uint32_t r = (v.u + 0x7FFFu + ((v.u >> 16) & 1u)) >> 16;
  return (short)r;
}
__device__ __forceinline__ float bf2f(short s) {
  union { uint32_t u; float f; } v; v.u = ((uint32_t)(uint16_t)s) << 16; return v.f;
}
__device__ __forceinline__ void gl_lds16(const float* g, float* l) {
  __builtin_amdgcn_global_load_lds(
      (const __attribute__((address_space(1))) uint32_t*)g,
      (__attribute__((address_space(3))) uint32_t*)l, 16, 0, 0);
}

// ---- prep: pre-swizzle w_def (frags [0,1536)) and w_off (frags [1536,1920)) into ws ----
__global__ __launch_bounds__(256) void prep_kernel(
    const float* __restrict__ w_off, const float* __restrict__ w_def, short8* __restrict__ ws)
{
  int gid = blockIdx.x * 256 + threadIdx.x;
  if (gid < 1536) {                      // q = (mt*6+ks)*64 + lane
    int mt = gid / 384, ks = (gid % 384) >> 6, ll = gid & 63;
    int m = mt * 16 + (ll & 15), rgq = ll >> 4;
    short8 v;
    #pragma unroll
    for (int jj = 0; jj < 8; ++jj) {
      int kk = ks * 32 + rgq * 8 + jj;
      int c = kk & 63, k3 = kk >> 6;
      v[jj] = f2bf(w_def[m * 192 + c * 3 + k3]);
    }
    ws[gid] = v;
  } else if (gid < 1920) {               // q = ks*64 + lane (rows 6..15 zero)
    int q = gid - 1536;
    int ks = q >> 6, ll = q & 63;
    int m = ll & 15, rgq = ll >> 4;
    short8 v;
    #pragma unroll
    for (int jj = 0; jj < 8; ++jj) {
      int kk = ks * 32 + rgq * 8 + jj;
      int c = kk & 63, k3 = kk >> 6;
      v[jj] = (m < 6) ? f2bf(w_off[m * 192 + c * 3 + k3]) : (short)0;
    }
    ws[gid] = v;
  }
}

__global__ __launch_bounds__(256, 3) void deform_main(
    const float* __restrict__ x, const float* __restrict__ b_off,
    const float* __restrict__ b_def, const short8* __restrict__ wfr,
    float* __restrict__ out)
{
  extern __shared__ char smem[];
  float* xrawf = (float*)(smem + XR_OFF);
  float* offs  = (float*)(smem + OFFS_OFF);
  float* stg   = (float*)(smem + XT_OFF);

  const int t = threadIdx.x, wv = t >> 6, l = t & 63, col = l & 15, rg = l >> 4;
  const int p = blockIdx.x;
  const int swz = (p & ~15) | ((p & 7) << 1) | ((p >> 3) & 1);

  float bo[6];
  #pragma unroll
  for (int i = 0; i < 6; ++i) bo[i] = b_off[i];
  float4 bdv[4];
  #pragma unroll
  for (int mt = 0; mt < 4; ++mt) bdv[mt] = *(const float4*)(b_def + mt * 16 + rg * 4);

  // ---- prologue: DMA tile 0 into xraw (32 x 1KB wave instructions) ----
  {
    int tn = swz;
    int wt = tn % 12, bh = tn / 12, h = bh % 96, b = bh / 96;
    const float* xb = x + (size_t)b * 9437184 + h * 96 + wt * 8;
    #pragma unroll
    for (int s = 0; s < 8; ++s) {
      int q = wv * 8 + s;
      int R = q * 32 + (l >> 1);               // row = c*16+n, 32B/row
      gl_lds16(xb + (size_t)R * 9216 + (l & 1) * 4, xrawf + q * 256);
    }
  }

  for (int j = 0; j < 3; ++j) {
    const int tn = swz + 768 * j;
    const int wt = tn % 12, bh = tn / 12, h = bh % 96, b = bh / 96;
    const int w0 = wt * 8;

    __syncthreads();   // drains this tile's DMA (vmcnt 0); prev-tile stg reads done

    // ---- transpose + cvt: xraw fp32 [c][n][w] -> xs_t bf16 [pos][c] ----
    #pragma unroll
    for (int i = 0; i < 4; ++i) {
      int item = t + 256 * i;                // 1024 = 128 pos x 8 cgroups
      int pos = item & 127, cg = item >> 7;
      int n = pos >> 3, w = pos & 7;
      short8 v;
      #pragma unroll
      for (int jj = 0; jj < 8; ++jj)
        v[jj] = f2bf(xrawf[((cg * 8 + jj) * 16 + n) * 8 + w]);
      *(short8*)(smem + XT_OFF + pos * 144 + cg * 16) = v;
    }
    __syncthreads();   // xs_t complete; xraw dead

    // ---- issue next tile's DMA now; drains behind conv+GEMM+epilogue ----
    if (j < 2) {
      int tn2 = tn + 768;
      int wt2 = tn2 % 12, bh2 = tn2 / 12, h2 = bh2 % 96, b2 = bh2 / 96;
      const float* xb2 = x + (size_t)b2 * 9437184 + h2 * 96 + wt2 * 8;
      #pragma unroll
      for (int s = 0; s < 8; ++s) {
        int q = wv * 8 + s;
        int R = q * 32 + (l >> 1);
        gl_lds16(xb2 + (size_t)R * 9216 + (l & 1) * 4, xrawf + q * 256);
      }
    }

    // ---- offsets conv via MFMA; offs produced & consumed by the SAME wave ----
    {
      f32x4 cacc[2] = {{0.f,0.f,0.f,0.f},{0.f,0.f,0.f,0.f}};
      const short8 zero = {0,0,0,0,0,0,0,0};
      for (int ks = 0; ks < 6; ++ks) {
        short8 av = wfr[1536 + ks * 64 + l];
        int k3 = ks >> 1;
        #pragma unroll
        for (int nt2 = 0; nt2 < 2; ++nt2) {
          int pos = (wv * 2 + nt2) * 16 + col;
          int n = pos >> 3, w = pos & 7;
          int row = n + k3 - 1;
          bool valid = (row >= 0) && (row < 16);
          int rcl = min(max(row, 0), 15);
          short8 bv = *(short8*)(smem + XT_OFF + (rcl * 8 + w) * 144 + rg * 16 + (ks & 1) * 64);
          bv = valid ? bv : zero;
          cacc[nt2] = __builtin_amdgcn_mfma_f32_16x16x32_bf16(av, bv, cacc[nt2], 0, 0, 0);
        }
      }
      #pragma unroll
      for (int nt2 = 0; nt2 < 2; ++nt2) {
        int pos = (wv * 2 + nt2) * 16 + col;
        #pragma unroll
        for (int r = 0; r < 4; ++r) {
          int rowo = rg * 4 + r;
          if (rowo < 6) offs[rowo * 128 + pos] = cacc[nt2][r];
        }
      }
    }
    // no barrier: same-wave LDS ordering (lgkmcnt) suffices

    // ---- interp params, per-lane in registers ----
    float a0v[3][2], a1v[3][2]; int rb[3][2];
    #pragma unroll
    for (int k = 0; k < 3; ++k) {
      #pragma unroll
      for (int nt2 = 0; nt2 < 2; ++nt2) {
        int pos = (wv * 2 + nt2) * 16 + col;
        int n = pos >> 3, w = pos & 7;
        float oy = offs[(2 * k) * 128 + pos] + bo[2 * k];
        float ox = offs[(2 * k + 1) * 128 + pos] + bo[2 * k + 1];
        float px = (float)(n - 1 + k) + ox;
        float x0f = floorf(px);
        float fx = px - x0f;
        int x0 = (int)x0f;
        float wy = fmaxf(0.f, 1.f - fabsf(oy));
        float wt1v = fx * wy;
        float wt0v = wy - wt1v;
        float a0, a1; int r0;
        if (x0 >= 0 && x0 < 15)  { r0 = x0; a0 = wt0v; a1 = wt1v; }
        else if (x0 == 15)       { r0 = 14; a0 = 0.f;  a1 = wt0v; }  // only row 15 (=x0)
        else if (x0 == -1)       { r0 = 0;  a0 = wt1v; a1 = 0.f;  }  // only row 0 (=x1)
        else                     { r0 = 0;  a0 = 0.f;  a1 = 0.f;  }
        a0v[k][nt2] = a0; a1v[k][nt2] = a1;
        rb[k][nt2] = (r0 * 8 + w) * 144;
      }
    }

    // ---- main GEMM: 64 o x 32 pos per wave, K=192; B-frags from taps on the fly ----
    f32x4 acc[4][2];
    #pragma unroll
    for (int mt = 0; mt < 4; ++mt) {
      #pragma unroll
      for (int nt2 = 0; nt2 < 2; ++nt2) {
        acc[mt][nt2][0] = bdv[mt].x; acc[mt][nt2][1] = bdv[mt].y;
        acc[mt][nt2][2] = bdv[mt].z; acc[mt][nt2][3] = bdv[mt].w;
      }
    }
    #pragma unroll 1
    for (int k3 = 0; k3 < 3; ++k3) {
      #pragma unroll
      for (int ks2 = 0; ks2 < 2; ++ks2) {
        int ks = k3 * 2 + ks2;
        short8 A[4];
        #pragma unroll
        for (int mt = 0; mt < 4; ++mt) A[mt] = wfr[(mt * 6 + ks) * 64 + l];
        #pragma unroll
        for (int nt2 = 0; nt2 < 2; ++nt2) {
          const char* base = smem + XT_OFF + rb[k3][nt2] + rg * 16 + ks2 * 64;
          short8 x0 = *(const short8*)base;
          short8 x1 = *(const short8*)(base + 1152);   // tap row r0+1 (stride 144 x 8)
          short8 bv;
          #pragma unroll
          for (int jj = 0; jj < 8; ++jj)
            bv[jj] = f2bf(a0v[k3][nt2] * bf2f(x0[jj]) + a1v[k3][nt2] * bf2f(x1[jj]));
          #pragma unroll
          for (int mt = 0; mt < 4; ++mt)
            acc[mt][nt2] = __builtin_amdgcn_mfma_f32_16x16x32_bf16(A[mt], bv, acc[mt][nt2], 0, 0, 0);
        }
      }
    }
    __syncthreads();   // xs_t dead; reuse as epilogue staging (xraw holds next-tile DMA!)

    // ---- epilogue: 2 passes of 32 o through stg [32][132], full-32B float4 stores ----
    float* ob = out + (size_t)b * 9437184 + h * 96 + w0;
    #pragma unroll 1
    for (int pp = 0; pp < 2; ++pp) {
      #pragma unroll
      for (int mt2 = 0; mt2 < 2; ++mt2) {
        int mt = pp * 2 + mt2;
        #pragma unroll
        for (int nt2 = 0; nt2 < 2; ++nt2) {
          int pos = (wv * 2 + nt2) * 16 + col;
          #pragma unroll
          for (int r = 0; r < 4; ++r) {
            int ol = mt2 * 16 + rg * 4 + r;
            stg[ol * 132 + pos] = acc[mt][nt2][r];
          }
        }
      }
      __syncthreads();
      #pragma unroll
      for (int i = 0; i < 4; ++i) {
        int s2 = t + 256 * i;                 // 1024 = 32 o x 16 n x 2 half
        int q = s2 >> 1, half = s2 & 1;
        int ol = q >> 4, n = q & 15;
        int o = pp * 32 + ol;
        float4 v = *(float4*)(stg + ol * 132 + n * 8 + half * 4);
        *(float4*)(ob + (size_t)(o * 16 + n) * 9216 + half * 4) = v;
      }
      if (pp == 0) __syncthreads();           // store reads done before pass-2 stg writes
    }
  }
}

extern "C" void kernel_launch(void* const* d_in, const int* in_sizes, int n_in,
                              void* d_out, int out_size, void* d_ws, size_t ws_size,
                              hipStream_t stream) {
  (void)in_sizes; (void)n_in; (void)ws_size; (void)out_size;
  const float* x     = (const float*)d_in[0];
  const float* w_off = (const float*)d_in[1];
  const float* b_off = (const float*)d_in[2];
  const float* w_def = (const float*)d_in[3];
  const float* b_def = (const float*)d_in[4];
  float* out = (float*)d_out;
  short8* wfr = (short8*)d_ws;   // 1920 * 16B = 30720 B of scratch

  (void)hipFuncSetAttribute((const void*)deform_main,
                            hipFuncAttributeMaxDynamicSharedMemorySize, LDS_BYTES);
  prep_kernel<<<dim3(8), dim3(256), 0, stream>>>(w_off, w_def, wfr);
  deform_main<<<dim3(768), dim3(256), LDS_BYTES, stream>>>(x, b_off, b_def, wfr, out);
}

// Round 7
// 182.664 us; speedup vs baseline: 1.3606x; 1.3606x over previous
//
#include <hip/hip_runtime.h>
#include <stdint.h>

// DeformableFusionAcrossFocus — round 7: r4 skeleton + no-scratch params (fully
// unrolled k3) + 4 blocks/CU via LDS overlay + XCD pair swizzle + 4 barriers/tile.
// x:(2,64,16,96,96) f32 | w_off:(6,64,3) | b_off:(6) | w_def:(64,64,3) | b_def:(64) -> out f32
// Tile = (b,h,8w): pos = n*8+w in [0,128). Grid 2304 blocks, 1 tile each.
// Block p -> tile (p&~15)|((p&7)<<1)|((p>>3)&1): blocks p,p+8 (same XCD under
// round-robin) get adjacent w-tiles -> shared 64B HBM lines in that XCD's L2.
// k-permutation kk -> (c = kk&63, k3 = kk>>6), shared by A-frag prep and B-frag builders.
// Waves split by pos: wave wv owns pos in [wv*32, wv*32+32), all 64 output channels;
// conv offsets, interp params and GEMM for those pos are same-wave (no barrier).

typedef __attribute__((ext_vector_type(8))) short short8;
typedef __attribute__((ext_vector_type(4))) float f32x4;

// LDS (bytes):
//  [0,18432)      xs_t bf16 [pos][72 shorts] (row stride 144B; 64 c used + 8 pad)
//  [18432,34816)  xstage bf16 [c*128 + n*8 + w] (dead after transpose)
//  [18432,21504)  offs f32 [6][128] (overlays dead xstage; same-wave produce/consume)
//  [0,33792)      epilogue staging f32 [64 o][132] (overlays everything post-GEMM)
#define XT_OFF   0
#define XG_OFF   18432
#define OFFS_OFF 18432
#define LDS_BYTES 34816   // 4 blocks/CU: 4*34816 = 139264 <= 163840

__device__ __forceinline__ short f2bf(float f) {
  union { float f; uint32_t u; } v; v.f = f;
  uint32_t r = (v.u + 0x7FFFu + ((v.u >> 16) & 1u)) >> 16;
  return (short)r;
}
__device__ __forceinline__ float bf2f(short s) {
  union { uint32_t u; float f; } v; v.u = ((uint32_t)(uint16_t)s) << 16; return v.f;
}

// ---- prep: pre-swizzle w_def (frags [0,1536)) and w_off (frags [1536,1920)) into ws ----
__global__ __launch_bounds__(256) void prep_kernel(
    const float* __restrict__ w_off, const float* __restrict__ w_def, short8* __restrict__ ws)
{
  int gid = blockIdx.x * 256 + threadIdx.x;
  if (gid < 1536) {                      // q = (mt*6+ks)*64 + lane
    int mt = gid / 384, ks = (gid % 384) >> 6, ll = gid & 63;
    int m = mt * 16 + (ll & 15), rgq = ll >> 4;
    short8 v;
    #pragma unroll
    for (int jj = 0; jj < 8; ++jj) {
      int kk = ks * 32 + rgq * 8 + jj;
      int c = kk & 63, k3 = kk >> 6;
      v[jj] = f2bf(w_def[m * 192 + c * 3 + k3]);
    }
    ws[gid] = v;
  } else if (gid < 1920) {               // q = ks*64 + lane (rows 6..15 zero)
    int q = gid - 1536;
    int ks = q >> 6, ll = q & 63;
    int m = ll & 15, rgq = ll >> 4;
    short8 v;
    #pragma unroll
    for (int jj = 0; jj < 8; ++jj) {
      int kk = ks * 32 + rgq * 8 + jj;
      int c = kk & 63, k3 = kk >> 6;
      v[jj] = (m < 6) ? f2bf(w_off[m * 192 + c * 3 + k3]) : (short)0;
    }
    ws[gid] = v;
  }
}

__global__ __launch_bounds__(256, 4) void deform_main(
    const float* __restrict__ x, const float* __restrict__ b_off,
    const float* __restrict__ b_def, const short8* __restrict__ wfr,
    float* __restrict__ out)
{
  extern __shared__ char smem[];
  uint16_t* xst = (uint16_t*)(smem + XG_OFF);
  float* offs   = (float*)(smem + OFFS_OFF);
  float* stg    = (float*)(smem + XT_OFF);

  const int t = threadIdx.x, wv = t >> 6, l = t & 63, col = l & 15, rg = l >> 4;
  const int p = blockIdx.x;
  const int tn = (p & ~15) | ((p & 7) << 1) | ((p >> 3) & 1);
  const int wt = tn % 12, bh = tn / 12;
  const int h = bh % 96, b = bh / 96, w0 = wt * 8;
  const float* xb = x + (size_t)b * 9437184 + h * 96 + w0;

  // ---- stage x -> bf16 xstage [c][n][w] (coalesced: 2 lanes per 32B row) ----
  #pragma unroll
  for (int i = 0; i < 8; ++i) {
    int r = (t >> 1) + i * 128, half = t & 1;       // r = c*16+n
    float4 v = *(const float4*)(xb + (size_t)r * 9216 + half * 4);
    uint32_t p0 = (uint32_t)(uint16_t)f2bf(v.x) | ((uint32_t)(uint16_t)f2bf(v.y) << 16);
    uint32_t p1 = (uint32_t)(uint16_t)f2bf(v.z) | ((uint32_t)(uint16_t)f2bf(v.w) << 16);
    uint2 pk; pk.x = p0; pk.y = p1;
    *(uint2*)(xst + r * 8 + half * 4) = pk;
  }
  __syncthreads();

  // ---- transpose -> xs_t[pos][c] (b128 writes; stride 144B) ----
  #pragma unroll
  for (int i = 0; i < 4; ++i) {
    int item = t + 256 * i;                // 1024 = 128 pos x 8 cgroups
    int pos = item & 127, cg = item >> 7;
    short8 v;
    #pragma unroll
    for (int jj = 0; jj < 8; ++jj) v[jj] = (short)xst[(cg * 8 + jj) * 128 + pos];
    *(short8*)(smem + XT_OFF + pos * 144 + cg * 16) = v;
  }
  __syncthreads();   // xs_t complete; xstage dead (offs overlays it)

  // ---- offsets conv via MFMA; offs produced & consumed by the SAME wave ----
  {
    f32x4 cacc[2] = {{0.f,0.f,0.f,0.f},{0.f,0.f,0.f,0.f}};
    const short8 zero = {0,0,0,0,0,0,0,0};
    #pragma unroll
    for (int ks = 0; ks < 6; ++ks) {
      short8 av = wfr[1536 + ks * 64 + l];
      int k3 = ks >> 1;
      #pragma unroll
      for (int nt2 = 0; nt2 < 2; ++nt2) {
        int pos = (wv * 2 + nt2) * 16 + col;
        int n = pos >> 3, w = pos & 7;
        int row = n + k3 - 1;
        bool valid = (row >= 0) && (row < 16);
        int rcl = min(max(row, 0), 15);
        short8 bv = *(short8*)(smem + XT_OFF + (rcl * 8 + w) * 144 + rg * 16 + (ks & 1) * 64);
        bv = valid ? bv : zero;
        cacc[nt2] = __builtin_amdgcn_mfma_f32_16x16x32_bf16(av, bv, cacc[nt2], 0, 0, 0);
      }
    }
    #pragma unroll
    for (int nt2 = 0; nt2 < 2; ++nt2) {
      int pos = (wv * 2 + nt2) * 16 + col;
      #pragma unroll
      for (int r = 0; r < 4; ++r) {
        int rowo = rg * 4 + r;
        if (rowo < 6) offs[rowo * 128 + pos] = cacc[nt2][r];
      }
    }
  }
  // no barrier: same-wave LDS ordering suffices

  // ---- interp params, per-lane in registers (all loop indices constant) ----
  float a0v[3][2], a1v[3][2]; int rb[3][2];
  #pragma unroll
  for (int k = 0; k < 3; ++k) {
    #pragma unroll
    for (int nt2 = 0; nt2 < 2; ++nt2) {
      int pos = (wv * 2 + nt2) * 16 + col;
      int n = pos >> 3, w = pos & 7;
      float oy = offs[(2 * k) * 128 + pos] + b_off[2 * k];
      float ox = offs[(2 * k + 1) * 128 + pos] + b_off[2 * k + 1];
      float px = (float)(n - 1 + k) + ox;
      float x0f = floorf(px);
      float fx = px - x0f;
      int x0 = (int)x0f;
      float wy = fmaxf(0.f, 1.f - fabsf(oy));
      float wt1v = fx * wy;
      float wt0v = wy - wt1v;
      float a0, a1; int r0;
      if (x0 >= 0 && x0 < 15)  { r0 = x0; a0 = wt0v; a1 = wt1v; }
      else if (x0 == 15)       { r0 = 14; a0 = 0.f;  a1 = wt0v; }  // only row 15 (=x0)
      else if (x0 == -1)       { r0 = 0;  a0 = wt1v; a1 = 0.f;  }  // only row 0 (=x1)
      else                     { r0 = 0;  a0 = 0.f;  a1 = 0.f;  }
      a0v[k][nt2] = a0; a1v[k][nt2] = a1;
      rb[k][nt2] = (r0 * 8 + w) * 144;
    }
  }

  // ---- main GEMM: 64 o x 32 pos per wave, K=192; FULLY UNROLLED (no scratch) ----
  f32x4 acc[4][2];
  #pragma unroll
  for (int mt = 0; mt < 4; ++mt) {
    float4 bd = *(const float4*)(b_def + mt * 16 + rg * 4);
    #pragma unroll
    for (int nt2 = 0; nt2 < 2; ++nt2) {
      acc[mt][nt2][0] = bd.x; acc[mt][nt2][1] = bd.y;
      acc[mt][nt2][2] = bd.z; acc[mt][nt2][3] = bd.w;
    }
  }
  #pragma unroll
  for (int k3 = 0; k3 < 3; ++k3) {
    #pragma unroll
    for (int ks2 = 0; ks2 < 2; ++ks2) {
      int ks = k3 * 2 + ks2;
      short8 A[4];
      #pragma unroll
      for (int mt = 0; mt < 4; ++mt) A[mt] = wfr[(mt * 6 + ks) * 64 + l];
      #pragma unroll
      for (int nt2 = 0; nt2 < 2; ++nt2) {
        const char* base = smem + XT_OFF + rb[k3][nt2] + rg * 16 + ks2 * 64;
        short8 x0 = *(const short8*)base;
        short8 x1 = *(const short8*)(base + 1152);   // tap row r0+1 (8 x stride 144)
        short8 bv;
        #pragma unroll
        for (int jj = 0; jj < 8; ++jj)
          bv[jj] = f2bf(a0v[k3][nt2] * bf2f(x0[jj]) + a1v[k3][nt2] * bf2f(x1[jj]));
        #pragma unroll
        for (int mt = 0; mt < 4; ++mt)
          acc[mt][nt2] = __builtin_amdgcn_mfma_f32_16x16x32_bf16(A[mt], bv, acc[mt][nt2], 0, 0, 0);
      }
    }
  }
  __syncthreads();   // xs_t + params dead; stg overlays [0,33792)

  // ---- epilogue: stage [64 o][132] f32, then full-32B float4 stores ----
  #pragma unroll
  for (int mt = 0; mt < 4; ++mt) {
    #pragma unroll
    for (int nt2 = 0; nt2 < 2; ++nt2) {
      int pos = (wv * 2 + nt2) * 16 + col;
      #pragma unroll
      for (int r = 0; r < 4; ++r) {
        int o = mt * 16 + rg * 4 + r;
        stg[o * 132 + pos] = acc[mt][nt2][r];
      }
    }
  }
  __syncthreads();
  float* ob = out + (size_t)b * 9437184 + h * 96 + w0;
  #pragma unroll
  for (int i = 0; i < 8; ++i) {
    int s2 = t + 256 * i;                 // 2048 = 64 o x 16 n x 2 half
    int q = s2 >> 1, half = s2 & 1;
    int o = q >> 4, n = q & 15;
    float4 v = *(float4*)(stg + o * 132 + n * 8 + half * 4);
    *(float4*)(ob + (size_t)(o * 16 + n) * 9216 + half * 4) = v;
  }
}

extern "C" void kernel_launch(void* const* d_in, const int* in_sizes, int n_in,
                              void* d_out, int out_size, void* d_ws, size_t ws_size,
                              hipStream_t stream) {
  (void)in_sizes; (void)n_in; (void)ws_size; (void)out_size;
  const float* x     = (const float*)d_in[0];
  const float* w_off = (const float*)d_in[1];
  const float* b_off = (const float*)d_in[2];
  const float* w_def = (const float*)d_in[3];
  const float* b_def = (const float*)d_in[4];
  float* out = (float*)d_out;
  short8* wfr = (short8*)d_ws;   // 1920 * 16B = 30720 B of scratch

  (void)hipFuncSetAttribute((const void*)deform_main,
                            hipFuncAttributeMaxDynamicSharedMemorySize, LDS_BYTES);
  prep_kernel<<<dim3(8), dim3(256), 0, stream>>>(w_off, w_def, wfr);
  deform_main<<<dim3(2304), dim3(256), LDS_BYTES, stream>>>(x, b_off, b_def, wfr, out);
}